// Round 15
// baseline (227.094 us; speedup 1.0000x reference)
//
#include <hip/hip_runtime.h>
#include <hip/hip_bf16.h>
#include <cstdint>
#include <cstddef>

// Problem constants (fixed by the reference)
#define BATCH 128
#define SEQ   512
#define DIM   1024
#define MROWS (BATCH * SEQ)          // 65536
#define NT    32                     // K sub-tiles of 32 (DIM/32)

typedef short short8 __attribute__((ext_vector_type(8)));
typedef __bf16 bf16x8 __attribute__((ext_vector_type(8)));
typedef float f32x4 __attribute__((ext_vector_type(4)));

// ---------- MFMA wrapper: accept either builtin signature (short8 or bf16x8) ----------
template <typename VA> struct other_frag { using type = bf16x8; };
template <> struct other_frag<bf16x8> { using type = short8; };

template <typename VA>
__device__ __forceinline__ auto try_mfma(VA a, VA b, f32x4 c, int)
    -> decltype(__builtin_amdgcn_mfma_f32_16x16x32_bf16(a, b, c, 0, 0, 0)) {
  return __builtin_amdgcn_mfma_f32_16x16x32_bf16(a, b, c, 0, 0, 0);
}
template <typename VA>
__device__ __forceinline__ f32x4 try_mfma(VA a, VA b, f32x4 c, long) {
  using O = typename other_frag<VA>::type;
  O a2 = __builtin_bit_cast(O, a);
  O b2 = __builtin_bit_cast(O, b);
  return __builtin_amdgcn_mfma_f32_16x16x32_bf16(a2, b2, c, 0, 0, 0);
}
__device__ __forceinline__ f32x4 mfma_bf16(short8 a, short8 b, f32x4 c) {
  return try_mfma(a, b, c, 0);
}

// ---------- helpers ----------
__device__ __forceinline__ unsigned short f32_to_bf16(float f) {
  union { float f; uint32_t u; } v; v.f = f;
  uint32_t u = v.u;
  u += 0x7FFFu + ((u >> 16) & 1u);   // round-to-nearest-even
  return (unsigned short)(u >> 16);
}

// 8 x f32 -> 8 x bf16 (RNE)
__device__ __forceinline__ short8 cvt8(f32x4 a, f32x4 b) {
  bf16x8 o;
  o[0] = (__bf16)a[0]; o[1] = (__bf16)a[1]; o[2] = (__bf16)a[2]; o[3] = (__bf16)a[3];
  o[4] = (__bf16)b[0]; o[5] = (__bf16)b[1]; o[6] = (__bf16)b[2]; o[7] = (__bf16)b[3];
  return __builtin_bit_cast(short8, o);
}

__device__ __forceinline__ void gload_lds16(const void* g, void* l) {
  __builtin_amdgcn_global_load_lds(
      (__attribute__((address_space(1))) void*)g,
      (__attribute__((address_space(3))) void*)l,
      16, 0, 0);
}

__device__ __forceinline__ float fast_tanh(float x) {
  x = fminf(fmaxf(x, -15.0f), 15.0f);
  float e = __expf(2.0f * x);
  return (e - 1.0f) / (e + 1.0f);
}

// ---------- kernel 1: W1 (D x D) -> W1t bf16 (transposed, [e][d]) ----------
__global__ __launch_bounds__(256) void w1t_kernel(const float* __restrict__ W1,
                                                  unsigned short* __restrict__ W1t) {
  __shared__ float tile[64][65];
  int bx = blockIdx.x & 15;    // e-tile
  int by = blockIdx.x >> 4;    // d-tile
  int t = threadIdx.x;
  int c = t & 63, r0 = t >> 6;
#pragma unroll
  for (int i = 0; i < 16; i++) {
    int r = i * 4 + r0;
    tile[r][c] = W1[(size_t)(by * 64 + r) * DIM + bx * 64 + c];
  }
  __syncthreads();
#pragma unroll
  for (int i = 0; i < 16; i++) {
    int r = i * 4 + r0;
    W1t[(size_t)(bx * 64 + r) * DIM + by * 64 + c] = f32_to_bf16(tile[c][r]);
  }
}

// ---------- kernel 2: 256x256 GEMM, A fp32 global->reg(3 sets)->bf16 LDS ----------
// C[m][e] = sum_d bf16(X[m][d]) * W1t[e][d]; scores[m] += sum_e tanh(C+b1[e])*w2[e]
//
// R14 skeleton (4Mx2N waves, counted vmcnt + one raw barrier per K32-subtile,
// XCD-chunked grid) with A stored BF16 in LDS:
//   - R14 is LDS-read-bound (128 KB/CU/subtile).  bf16 A -> 12 b128/wave =
//     96 KB/CU/subtile (-25%), and consume-side cvt_pk eliminated.
//   - R13's failure was 1-iter A-global latency cover.  Here: 3 statically-
//     named rA sets (48 VGPR), rotation aligned to a 3-unrolled loop:
//     A(T) loaded at iter T-3 into set T%3, ds_written at iter T-1 to LDS
//     slot T%3, consumed at iter T  ->  2 iterations of latency cover.
//   - VMEM queue/thread at iter S top (oldest->newest):
//     [A(S+1)4, B(S)2, A(S+2)4, B(S+1)2] -> vmcnt(6) retires A(S+1)+B(S).
//     Tails: S=30 vmcnt(2), S=31 vmcnt(0).
//   - A-write visibility: write issues before this iter's ds_reads
//     (sched_barrier pin); in-order DS retirement => reads' lgkmcnt also
//     retires the writes before the wave reaches the next barrier.
//   - A-slot reuse: slot (S+1)%3 written at iter S was last read at iter S-2,
//     done before barrier(S-1) < barrier(S).  B ring identical to R14.
// Bank safety (R10-validated stride-8 model): A-write wOff = R13's pattern
// (measured 0); A-read/B-read = the measured-0 row-pair XOR scheme.
// LDS: A ring-3 x 16 KB + B ring-3 x 16 KB = 96 KB.
__global__ __launch_bounds__(512, 2) void gemm_score_kernel(
    const float* __restrict__ X,              // [MROWS][DIM] fp32
    const unsigned short* __restrict__ W1t,   // [DIM][DIM]  (e-major)
    const float* __restrict__ b1,
    const float* __restrict__ w2,
    float* __restrict__ scores) {             // [MROWS]
  __shared__ __align__(16) char lds[98304];   // A: [0,48K)  B: [48K,96K)

  const int tid = threadIdx.x;
  const int lane = tid & 63;
  const int w = tid >> 6;                     // wave 0..7
  const int wr = w >> 1, wc = w & 1;          // 4 x 2 wave grid, 64x128 each

  // chunked XCD swizzle: 1024 blocks, 8 XCDs, n-fastest within each chunk
  const int bx = blockIdx.x;
  const int swz = (bx & 7) * 128 + (bx >> 3);
  const int m0 = (swz >> 2) * 256;
  const int n0 = (swz & 3) * 256;

  // ---- A staging: thread t owns row = t>>1, floats (t&1)*16 .. +16
  const float* aSrcT = X + (size_t)(m0 + (tid >> 1)) * DIM + (tid & 1) * 16;
  // A LDS write offsets (2 granules, i=0,1): srow = t>>2,
  // j' = ((t>>1)&1)*4 + (t&1)*2 + i, js = j' ^ (srow&7).  (R13: measured 0.)
  int wOff[2];
  {
    int srow = tid >> 2;
    int j0 = ((tid >> 1) & 1) * 4 + (tid & 1) * 2;
#pragma unroll
    for (int i = 0; i < 2; i++)
      wOff[i] = srow * 128 + ((j0 + i) ^ (srow & 7)) * 16;
  }

  // ---- B staging sources: 2 chunks/thread, sc = i*512 + tid (16B bf16 chunks)
  const unsigned short* bSrc[2];
#pragma unroll
  for (int i = 0; i < 2; i++) {
    int sc = i * 512 + tid;
    int srow = sc >> 3;
    int j = (sc & 7) ^ (srow & 7);
    int row = srow * 2 + (j >> 2);
    bSrc[i] = W1t + (size_t)(n0 + row) * DIM + (j & 3) * 8;
  }

  // ---- fragment LDS byte offsets (measured-0 row-pair XOR scheme)
  int aOff[4];                                // A: within a 16KB bf16 buffer
#pragma unroll
  for (int mi = 0; mi < 4; mi++) {
    int row = wr * 64 + mi * 16 + (lane & 15);
    int srow = row >> 1;
    int ic = ((row & 1) * 4 + (lane >> 4)) ^ (srow & 7);
    aOff[mi] = srow * 128 + ic * 16;
  }
  int bOff[8];                                // B: within a 16KB bf16 buffer
#pragma unroll
  for (int ni = 0; ni < 8; ni++) {
    int row = wc * 128 + ni * 16 + (lane & 15);
    int srow = row >> 1;
    int ic = ((row & 1) * 4 + (lane >> 4)) ^ (srow & 7);
    bOff[ni] = srow * 128 + ic * 16;
  }

  f32x4 acc[4][8];
#pragma unroll
  for (int mi = 0; mi < 4; mi++)
#pragma unroll
    for (int ni = 0; ni < 8; ni++)
      acc[mi][ni] = (f32x4){0.f, 0.f, 0.f, 0.f};

  f32x4 sA0[4], sA1[4], sA2[4];               // 3 A register sets (48 VGPR)
  short8 af[4], bfv[8];

#define LOAD_AS(SET, S) do {                                            \
    const float* p_ = aSrcT + (S) * 32;                                 \
    SET[0] = *(const f32x4*)(p_);                                       \
    SET[1] = *(const f32x4*)(p_ + 4);                                   \
    SET[2] = *(const f32x4*)(p_ + 8);                                   \
    SET[3] = *(const f32x4*)(p_ + 12);                                  \
  } while (0)

#define WRITE_A(SET, SLOT) do {                                         \
    char* aw_ = lds + (SLOT) * 16384;                                   \
    *(short8*)(aw_ + wOff[0]) = cvt8(SET[0], SET[1]);                   \
    *(short8*)(aw_ + wOff[1]) = cvt8(SET[2], SET[3]);                   \
  } while (0)

#define STAGE_B(S, SLOT) do {                                           \
    char* bb_ = lds + 49152 + (SLOT) * 16384;                           \
    const int koF_ = (S) * 32;                                          \
    gload_lds16(bSrc[0] + koF_, bb_ + w * 1024);                        \
    gload_lds16(bSrc[1] + koF_, bb_ + 8192 + w * 1024);                 \
  } while (0)

#define KITER(S, SETW, SETL, RS, WS, BS, W_, PFA, PFB, VMSTR) do {      \
    asm volatile("s_waitcnt vmcnt(" VMSTR ")" ::: "memory");            \
    __builtin_amdgcn_s_barrier();                                       \
    __builtin_amdgcn_sched_barrier(0);                                  \
    if (W_) WRITE_A(SETW, WS);                                          \
    __builtin_amdgcn_sched_barrier(0);                                  \
    if (PFA) LOAD_AS(SETL, (S) + 3);                                    \
    if (PFB) STAGE_B((S) + 2, BS);                                      \
    const char* bufA_ = lds + (RS) * 16384;                             \
    const char* bufB_ = lds + 49152 + (RS) * 16384;                     \
    _Pragma("unroll")                                                   \
    for (int mi = 0; mi < 4; mi++)                                      \
      af[mi] = *(const short8*)(bufA_ + aOff[mi]);                      \
    _Pragma("unroll")                                                   \
    for (int ni = 0; ni < 8; ni++)                                      \
      bfv[ni] = *(const short8*)(bufB_ + bOff[ni]);                     \
    __builtin_amdgcn_s_setprio(1);                                      \
    _Pragma("unroll")                                                   \
    for (int mi = 0; mi < 4; mi++)                                      \
      _Pragma("unroll")                                                 \
      for (int ni = 0; ni < 8; ni++)                                    \
        acc[mi][ni] = mfma_bf16(af[mi], bfv[ni], acc[mi][ni]);          \
    __builtin_amdgcn_s_setprio(0);                                      \
  } while (0)

  // prologue: A(0)->set0->slot0; A(1)->set1, B(0); A(2)->set2, B(1).
  // VMEM queue after prologue: [A(1)4, B(0)2, A(2)4, B(1)2]
  LOAD_AS(sA0, 0);
  asm volatile("s_waitcnt vmcnt(0)" ::: "memory");
  WRITE_A(sA0, 0);
  LOAD_AS(sA1, 1);
  STAGE_B(0, 0);
  LOAD_AS(sA2, 2);
  STAGE_B(1, 1);
  asm volatile("s_waitcnt lgkmcnt(0)" ::: "memory");  // slot-0 write drained

  // main: S = 0..26, unrolled by 3 (slot/set phases compile-time)
  for (int t = 0; t < 9; ++t) {
    const int S0 = 3 * t;
    KITER(S0,     sA1, sA0, 0, 1, 2, 1, 1, 1, "6");
    KITER(S0 + 1, sA2, sA1, 1, 2, 0, 1, 1, 1, "6");
    KITER(S0 + 2, sA0, sA2, 2, 0, 1, 1, 1, 1, "6");
  }
  // tails
  KITER(27, sA1, sA0, 0, 1, 2, 1, 1, 1, "6");   // loads A(30), B(29)
  KITER(28, sA2, sA1, 1, 2, 0, 1, 1, 1, "6");   // loads A(31), B(30)
  KITER(29, sA0, sA0, 2, 0, 1, 1, 0, 1, "6");   // B(31) only
  KITER(30, sA1, sA0, 0, 1, 2, 1, 0, 0, "2");   // write A(31)
  KITER(31, sA0, sA0, 1, 0, 0, 0, 0, 0, "0");

#undef KITER
#undef STAGE_B
#undef WRITE_A
#undef LOAD_AS

  // epilogue: scores[row] += sum over this wave's 128 cols of tanh(c + b1) * w2
  const int cg = lane >> 4;   // row group: rows cg*4 + j
  const int cl = lane & 15;   // col within fragment
#pragma unroll
  for (int mi = 0; mi < 4; mi++) {
    float p0 = 0.f, p1 = 0.f, p2 = 0.f, p3 = 0.f;
#pragma unroll
    for (int ni = 0; ni < 8; ni++) {
      int col = n0 + wc * 128 + ni * 16 + cl;
      float w2v = w2[col];
      float b1v = b1[col];
      p0 += fast_tanh(acc[mi][ni][0] + b1v) * w2v;
      p1 += fast_tanh(acc[mi][ni][1] + b1v) * w2v;
      p2 += fast_tanh(acc[mi][ni][2] + b1v) * w2v;
      p3 += fast_tanh(acc[mi][ni][3] + b1v) * w2v;
    }
#pragma unroll
    for (int off = 1; off < 16; off <<= 1) {
      p0 += __shfl_xor(p0, off);
      p1 += __shfl_xor(p1, off);
      p2 += __shfl_xor(p2, off);
      p3 += __shfl_xor(p3, off);
    }
    if (cl == 0) {
      int row = m0 + wr * 64 + mi * 16 + cg * 4;
      atomicAdd(&scores[row + 0], p0);
      atomicAdd(&scores[row + 1], p1);
      atomicAdd(&scores[row + 2], p2);
      atomicAdd(&scores[row + 3], p3);
    }
  }
}

// ---------- kernel 3: masked softmax + u_att + u_last (fp32 X) ----------
__global__ __launch_bounds__(256) void attn_uatt_kernel(
    const float* __restrict__ X,
    const float* __restrict__ scores,
    const int* __restrict__ mask,
    float* __restrict__ u_att,
    float* __restrict__ u_last) {
  const int b = blockIdx.x;
  const int half = blockIdx.y;            // d-range [half*512, half*512+512)
  const int tid = threadIdx.x;
  const int lane = tid & 63;
  const int wave = tid >> 6;

  __shared__ float attn[SEQ];
  __shared__ float rbuf[4];
  __shared__ float part[3][64 * 9];       // padded stride 9

  float s0 = scores[(size_t)b * SEQ + tid];
  float s1 = scores[(size_t)b * SEQ + 256 + tid];
  if (mask[(size_t)b * SEQ + tid]) s0 = -1000000000.0f;
  if (mask[(size_t)b * SEQ + 256 + tid]) s1 = -1000000000.0f;

  float mx = fmaxf(s0, s1);
#pragma unroll
  for (int off = 1; off < 64; off <<= 1) mx = fmaxf(mx, __shfl_xor(mx, off));
  if (lane == 0) rbuf[wave] = mx;
  __syncthreads();
  mx = fmaxf(fmaxf(rbuf[0], rbuf[1]), fmaxf(rbuf[2], rbuf[3]));

  float p0 = expf(s0 - mx), p1 = expf(s1 - mx);
  float sm = p0 + p1;
#pragma unroll
  for (int off = 1; off < 64; off <<= 1) sm += __shfl_xor(sm, off);
  __syncthreads();
  if (lane == 0) rbuf[wave] = sm;
  __syncthreads();
  sm = rbuf[0] + rbuf[1] + rbuf[2] + rbuf[3];
  float inv = 1.0f / sm;
  attn[tid] = p0 * inv;
  attn[tid + 256] = p1 * inv;
  __syncthreads();

  // u_last: exact fp32 copy of X[:, 511, :] (this block's 512-d half)
  if (tid < 128) {
    ((f32x4*)u_last)[(size_t)b * 256 + half * 128 + tid] =
        ((const f32x4*)X)[((size_t)b * SEQ + (SEQ - 1)) * 256 + half * 128 + tid];
  }

  // u_att[b][d] = sum_s attn[s] * X[b][s][d]; block covers 512 d (64 groups of 8)
  const int col = tid & 63;            // 8-float group within the half
  const int sh = tid >> 6;             // s-range split: [sh*128, sh*128+128)
  const f32x4* Xp = (const f32x4*)X + (size_t)b * SEQ * 256 + half * 128 + col * 2;
  f32x4 a0 = {0.f, 0.f, 0.f, 0.f}, a1 = {0.f, 0.f, 0.f, 0.f};
  for (int s = sh * 128; s < sh * 128 + 128; s++) {
    float wgt = attn[s];
    a0 += wgt * Xp[(size_t)s * 256];
    a1 += wgt * Xp[(size_t)s * 256 + 1];
  }
  if (sh) {
#pragma unroll
    for (int j = 0; j < 4; j++) part[sh - 1][col * 9 + j] = a0[j];
#pragma unroll
    for (int j = 0; j < 4; j++) part[sh - 1][col * 9 + 4 + j] = a1[j];
  }
  __syncthreads();
  if (sh == 0) {
#pragma unroll
    for (int j = 0; j < 4; j++)
      a0[j] += part[0][col * 9 + j] + part[1][col * 9 + j] + part[2][col * 9 + j];
#pragma unroll
    for (int j = 0; j < 4; j++)
      a1[j] += part[0][col * 9 + 4 + j] + part[1][col * 9 + 4 + j] + part[2][col * 9 + 4 + j];
    f32x4* dst = (f32x4*)(u_att + (size_t)b * DIM + half * 512 + col * 8);
    dst[0] = a0;
    dst[1] = a1;
  }
}

// ---------- launcher ----------
extern "C" void kernel_launch(void* const* d_in, const int* in_sizes, int n_in,
                              void* d_out, int out_size, void* d_ws, size_t ws_size,
                              hipStream_t stream) {
  const float* X    = (const float*)d_in[0];   // [128][512][1024] fp32
  const int*   mask = (const int*)d_in[1];     // [128][512] int32 (bool)
  const float* W1   = (const float*)d_in[2];   // [1024][1024]
  const float* b1   = (const float*)d_in[3];   // [1024]
  const float* w2   = (const float*)d_in[4];   // [1024]

  float* out    = (float*)d_out;
  float* u_last = out;                          // [128][1024]
  float* u_att  = out + BATCH * DIM;            // [128][1024]

  char* ws = (char*)d_ws;
  unsigned short* W1t = (unsigned short*)ws;                        // 2 MB
  float* scores = (float*)(ws + (size_t)DIM * DIM * 2);             // 256 KB

  hipMemsetAsync(scores, 0, MROWS * sizeof(float), stream);
  hipLaunchKernelGGL(w1t_kernel, dim3(256), dim3(256), 0, stream, W1, W1t);
  hipLaunchKernelGGL(gemm_score_kernel, dim3(1024), dim3(512), 0, stream,
                     X, W1t, b1, w2, scores);
  hipLaunchKernelGGL(attn_uatt_kernel, dim3(128, 2), dim3(256), 0, stream,
                     X, scores, mask, u_att, u_last);
}